// Round 2
// baseline (288.995 us; speedup 1.0000x reference)
//
#include <hip/hip_runtime.h>
#include <hip/hip_bf16.h>

#define NN 256
#define LL 128
#define BSZ 16
#define RR (BSZ * LL)   // 2048 rows = bs*L

// C[r,c] = mask[r] * dot(A[r,:], W[c,:]) + bias_c[c] + bias_bc[b(r),c]
// A: [2048][256] fp32; W: fp32 [256][ldw], k-contiguous rows (ldw = 256 or 512)
__global__ __launch_bounds__(256) void gemm_k(
    const float* __restrict__ A,
    const float* __restrict__ W, int ldw,
    const float* __restrict__ bias_c,   // [256] or null
    const float* __restrict__ bias_bc,  // [16][256] or null
    const float* __restrict__ maskp,    // [2048] or null
    float* __restrict__ O)              // [2048][256]
{
    __shared__ float As[32][34];  // [k][row], pad 34 (8B-aligned rows)
    __shared__ float Bs[32][68];  // [k][col], pad 68 (16B-aligned rows)
    const int tid = threadIdx.x;
    const int bx = blockIdx.x;       // c-tile 0..3
    const int by = blockIdx.y;       // r-tile 0..63
    const int arow = tid >> 3;       // 0..31
    const int akq  = (tid & 7) << 2; // 0,4,..,28
    const int bcc  = tid >> 2;       // 0..63
    const int bk8  = (tid & 3) << 3; // 0,8,16,24
    const int ty = tid >> 4;         // 0..15 -> rows ty*2, ty*2+1
    const int tx = tid & 15;         // 0..15 -> cols tx*4..tx*4+3
    const int gra = by * 32 + arow;
    const int gcb = bx * 64 + bcc;

    float acc[2][4] = {};

    for (int k0 = 0; k0 < NN; k0 += 32) {
        const float4 a4 = *(const float4*)(A + (size_t)gra * NN + k0 + akq);
        const float4 b0 = *(const float4*)(W + (size_t)gcb * ldw + k0 + bk8);
        const float4 b1 = *(const float4*)(W + (size_t)gcb * ldw + k0 + bk8 + 4);
        __syncthreads();
        As[akq + 0][arow] = a4.x;
        As[akq + 1][arow] = a4.y;
        As[akq + 2][arow] = a4.z;
        As[akq + 3][arow] = a4.w;
        Bs[bk8 + 0][bcc] = b0.x; Bs[bk8 + 1][bcc] = b0.y;
        Bs[bk8 + 2][bcc] = b0.z; Bs[bk8 + 3][bcc] = b0.w;
        Bs[bk8 + 4][bcc] = b1.x; Bs[bk8 + 5][bcc] = b1.y;
        Bs[bk8 + 6][bcc] = b1.z; Bs[bk8 + 7][bcc] = b1.w;
        __syncthreads();
        #pragma unroll
        for (int kk = 0; kk < 32; kk++) {
            const float2 a = *(const float2*)&As[kk][ty * 2];
            const float4 b = *(const float4*)&Bs[kk][tx * 4];
            acc[0][0] += a.x * b.x; acc[0][1] += a.x * b.y;
            acc[0][2] += a.x * b.z; acc[0][3] += a.x * b.w;
            acc[1][0] += a.y * b.x; acc[1][1] += a.y * b.y;
            acc[1][2] += a.y * b.z; acc[1][3] += a.y * b.w;
        }
    }

    const int r0 = by * 32 + ty * 2;
    const int c0 = bx * 64 + tx * 4;
    float badd[4] = {0.f, 0.f, 0.f, 0.f};
    if (bias_c) {
        #pragma unroll
        for (int j = 0; j < 4; j++) badd[j] = bias_c[c0 + j];
    }
    #pragma unroll
    for (int i = 0; i < 2; i++) {
        const int r = r0 + i;
        const float mval = maskp ? maskp[r] : 1.0f;
        const float* bbc = bias_bc ? (bias_bc + (size_t)(r >> 7) * NN + c0) : nullptr;
        float v[4];
        #pragma unroll
        for (int j = 0; j < 4; j++)
            v[j] = acc[i][j] * mval + badd[j] + (bbc ? bbc[j] : 0.f);
        *(float4*)(O + (size_t)r * NN + c0) = make_float4(v[0], v[1], v[2], v[3]);
    }
}

// Per (b,c): softmax over s of p[b,s,c]; agg = sigmoid(sum_s w*x);
// then aggU[b,c] = dot(agg[b,:], U2[c,:]) + updB[c]   (U2 = updW[:, 256:])
__global__ __launch_bounds__(256) void softagg_k(
    const float* __restrict__ p,       // [2048][256]
    const float* __restrict__ x,       // [2048][256]
    const float* __restrict__ updWi,   // [256][512]
    const float* __restrict__ updBi,   // [256]
    float* __restrict__ aggU)          // [16][256]
{
    __shared__ float sagg[NN];
    const int b = blockIdx.x;
    const int c = threadIdx.x;
    const float* pb = p + (size_t)b * LL * NN + c;
    const float* xb = x + (size_t)b * LL * NN + c;
    float m = -1e30f;
    #pragma unroll 16
    for (int s = 0; s < LL; s++) m = fmaxf(m, pb[(size_t)s * NN]);
    float den = 0.f, num = 0.f;
    #pragma unroll 16
    for (int s = 0; s < LL; s++) {
        const float e = __expf(pb[(size_t)s * NN] - m);
        den += e;
        num += e * xb[(size_t)s * NN];
    }
    const float a = num / den;
    const float sig = 1.f / (1.f + __expf(-a));
    sagg[c] = sig;
    __syncthreads();
    const float* u2 = updWi + (size_t)c * (2 * NN) + NN;
    float acc = 0.f;
    #pragma unroll
    for (int k = 0; k < NN; k += 4) {
        const float4 w4 = *(const float4*)(u2 + k);
        acc += sagg[k + 0] * w4.x;
        acc += sagg[k + 1] * w4.y;
        acc += sagg[k + 2] * w4.z;
        acc += sagg[k + 3] * w4.w;
    }
    aggU[(size_t)b * NN + c] = acc + updBi[c];
}

extern "C" void kernel_launch(void* const* d_in, const int* in_sizes, int n_in,
                              void* d_out, int out_size, void* d_ws, size_t ws_size,
                              hipStream_t stream) {
    const float* feat  = (const float*)d_in[0]; // [16][128][256]
    const float* mask  = (const float*)d_in[1]; // [16][128]
    const float* aggW  = (const float*)d_in[2]; // [3][256][256]
    const float* aggB  = (const float*)d_in[3]; // [3][256]
    const float* attnW = (const float*)d_in[4]; // [3][256][512]
    // d_in[5] = attnB: cancels in softmax (constant along the s axis)
    const float* updW  = (const float*)d_in[6]; // [3][256][512]
    const float* updB  = (const float*)d_in[7]; // [3][256]

    // ws layout: bufA (hid / p, aliased), bufB (x), aggU  (~4.2 MB fp32)
    float* bufA = (float*)d_ws;
    float* bufB = bufA + (size_t)RR * NN;
    float* aggU = bufB + (size_t)RR * NN;
    float* outF = (float*)d_out;

    const dim3 grid(4, 64), block(256);
    for (int i = 0; i < 3; i++) {
        // x = mask .* (hid @ aggW_i^T) + aggB_i   -> bufB
        gemm_k<<<grid, block, 0, stream>>>(
            i ? bufA : feat,
            aggW + (size_t)i * NN * NN, NN,
            aggB + (size_t)i * NN, nullptr, mask,
            bufB);
        // p = x @ W1^T   (W1 = attnW_i[:, :256])  -> bufA (overwrites dead hid)
        gemm_k<<<grid, block, 0, stream>>>(
            bufB,
            attnW + (size_t)i * NN * 2 * NN, 2 * NN,
            nullptr, nullptr, nullptr,
            bufA);
        // agg = sigmoid(softmax_s(p) . x);  aggU = agg @ U2^T + updB_i
        softagg_k<<<BSZ, NN, 0, stream>>>(
            bufA, bufB,
            updW + (size_t)i * NN * 2 * NN, updB + (size_t)i * NN, aggU);
        // hid' = x @ U1^T + aggU[b,:]   (U1 = updW_i[:, :256])
        gemm_k<<<grid, block, 0, stream>>>(
            bufB,
            updW + (size_t)i * NN * 2 * NN, 2 * NN,
            nullptr, aggU, nullptr,
            (i < 2) ? bufA : outF);
    }
}